// Round 5
// baseline (35.371 us; speedup 1.0000x reference)
//
#include <hip/hip_runtime.h>
#include <math.h>

#define NF 32
#define NE 64
#define NA 64
#define NP 496

typedef __attribute__((ext_vector_type(8))) _Float16 f16x8;
typedef __attribute__((ext_vector_type(4))) _Float16 f16x4;
typedef __attribute__((ext_vector_type(4))) float    f32x4;

// ---- pre-kernel: pack W1 (f32 64x64) into per-lane f16 MFMA A-fragments ----
// layout: wf[lane*64 + (s*4+mt)*8 + j] = W1[(s*32+g*8+j)*64 + mt*16 + nlane]
__global__ void prep_w1(const float* __restrict__ W1, _Float16* __restrict__ wf) {
    const int lane = threadIdx.x;        // 64 threads
    const int nl = lane & 15, g = lane >> 4;
    #pragma unroll
    for (int s = 0; s < 2; ++s)
        #pragma unroll
        for (int mt = 0; mt < 4; ++mt)
            #pragma unroll
            for (int j = 0; j < 8; ++j)
                wf[lane * 64 + (s * 4 + mt) * 8 + j] =
                    (_Float16)W1[(s * 32 + g * 8 + j) * NA + mt * 16 + nl];
}

__global__ __launch_bounds__(256, 4) void afm_fwd(
    const float* __restrict__ x,    // (B,32,64)
    const float* __restrict__ W1,   // (64,64)
    const float* __restrict__ b1,   // (64)
    const float* __restrict__ w2,   // (64,1)
    const float* __restrict__ b2,   // (1)
    const _Float16* __restrict__ wf,// packed W1 frags (or nullptr -> build here)
    float* __restrict__ out,        // (B,64)
    float* __restrict__ attn)       // (B,496)
{
    const int b     = blockIdx.x;
    const int tid   = threadIdx.x;
    const int lane  = tid & 63;
    const int wv    = tid >> 6;
    const int nlane = lane & 15;    // MFMA N-lane (pair within tile)
    const int g     = lane >> 4;    // k-group / C-row group

    __shared__ _Float16 xh[8][NF][8];               // 4096 B, frag read = 1 b128
    __shared__ float s_l[512];                      // logits -> exp
    __shared__ unsigned short s_rc[512];            // r | c<<8
    __shared__ float s_red_s[4];
    __shared__ __align__(16) float s_accv[4][NE];   // phase-3 per-wave partials

    // ---- stage x[b] -> f16 subtiled LDS ----
    const float* __restrict__ xb = x + (size_t)b * (NF * NE);
    #pragma unroll
    for (int k = 0; k < 2; ++k) {
        const int f   = (k * 256 + tid) * 4;        // flat float idx
        const float4 v = *(const float4*)(xb + f);
        const int row = f >> 6, e0 = f & 63;
        f16x4 hv = { (_Float16)v.x, (_Float16)v.y, (_Float16)v.z, (_Float16)v.w };
        *(f16x4*)&xh[e0 >> 3][row][e0 & 7] = hv;    // ds_write_b64
    }
    // ---- pair table via closed form (no divergent loop) ----
    for (int p = tid; p < 512; p += 256) {
        const int pp = (p < NP) ? p : NP - 1;
        const float sq = sqrtf((float)(3969 - 8 * pp));
        int r = (int)((63.0f - sq) * 0.5f);
        int st = (r * (63 - r)) >> 1;
        if (pp < st) { --r; st = (r * (63 - r)) >> 1; }
        else { const int st2 = ((r + 1) * (62 - r)) >> 1; if (pp >= st2) { ++r; st = st2; } }
        const int c = pp - st + r + 1;
        s_rc[p] = (unsigned short)(r | (c << 8));
    }

    // ---- W1 A-frags: fast path = 8 dwordx4 from packed ws ----
    f16x8 w1f[2][4];
    if (wf) {
        const f16x8* __restrict__ wfl = (const f16x8*)(wf + lane * 64);
        #pragma unroll
        for (int s = 0; s < 2; ++s)
            #pragma unroll
            for (int mt = 0; mt < 4; ++mt)
                w1f[s][mt] = wfl[s * 4 + mt];
    } else {
        #pragma unroll
        for (int s = 0; s < 2; ++s)
            #pragma unroll
            for (int mt = 0; mt < 4; ++mt)
                #pragma unroll
                for (int j = 0; j < 8; ++j)
                    w1f[s][mt][j] = (_Float16)W1[(s * 32 + g * 8 + j) * NA + mt * 16 + nlane];
    }

    f32x4 b1q[4], w2q[4];
    #pragma unroll
    for (int mt = 0; mt < 4; ++mt) {
        b1q[mt] = *(const f32x4*)(b1 + mt * 16 + g * 4);   // a = 16mt+4g+reg
        w2q[mt] = *(const f32x4*)(w2 + mt * 16 + g * 4);
    }
    const float bias2 = b2[0];
    __syncthreads();

    // ---- phase 1: logits. C' = W1^T(A) x inner^T(B): row=a-part, col=pair ----
    for (int t = wv; t < 31; t += 4) {
        const int p0 = t << 4;
        const unsigned short rc = s_rc[p0 + nlane];
        const int r = rc & 255, c = rc >> 8;

        f16x8 af[2];
        #pragma unroll
        for (int s = 0; s < 2; ++s) {
            const f16x8 xr8 = *(const f16x8*)&xh[4 * s + g][r][0];
            const f16x8 xc8 = *(const f16x8*)&xh[4 * s + g][c][0];
            af[s] = xr8 * xc8;                      // v_pk_mul_f16
        }

        f32x4 acc[4];
        #pragma unroll
        for (int mt = 0; mt < 4; ++mt) acc[mt] = b1q[mt];   // b1 folded into init
        #pragma unroll
        for (int s = 0; s < 2; ++s)
            #pragma unroll
            for (int mt = 0; mt < 4; ++mt)
                acc[mt] = __builtin_amdgcn_mfma_f32_16x16x32_f16(w1f[s][mt], af[s], acc[mt], 0, 0, 0);

        float logit = 0.0f;
        #pragma unroll
        for (int mt = 0; mt < 4; ++mt) {
            logit = fmaf(fmaxf(acc[mt][0], 0.0f), w2q[mt][0], logit);
            logit = fmaf(fmaxf(acc[mt][1], 0.0f), w2q[mt][1], logit);
            logit = fmaf(fmaxf(acc[mt][2], 0.0f), w2q[mt][2], logit);
            logit = fmaf(fmaxf(acc[mt][3], 0.0f), w2q[mt][3], logit);
        }
        logit += __shfl_xor(logit, 16);
        logit += __shfl_xor(logit, 32);
        if (lane < 16) s_l[p0 + lane] = logit + bias2;
    }
    __syncthreads();

    // ---- phase 2: softmax (no max-sub: logits O(+-10), fp32 exp safe) ----
    const float v0 = __expf(s_l[tid]);
    const float v1 = (tid < NP - 256) ? __expf(s_l[tid + 256]) : 0.0f;
    s_l[tid] = v0;
    if (tid < NP - 256) s_l[tid + 256] = v1;
    float sum = v0 + v1;
    #pragma unroll
    for (int off = 32; off > 0; off >>= 1) sum += __shfl_xor(sum, off);
    if (lane == 0) s_red_s[wv] = sum;
    __syncthreads();                               // covers exp-writes + partials
    const float inv = 1.0f / (s_red_s[0] + s_red_s[1] + s_red_s[2] + s_red_s[3]);

    float* __restrict__ attn_b = attn + (size_t)b * NP;
    attn_b[tid] = v0 * inv;
    if (tid < NP - 256) attn_b[tid + 256] = v1 * inv;

    // ---- phase 3: out[e] = inv * sum_p exp_p * inner[p][e], tile-recompute ----
    float oacc[2][8] = {{0}};
    for (int t = wv; t < 31; t += 4) {
        const int p0 = t << 4;
        const float ap = s_l[p0 + nlane];          // raw exp (fp32, no overflow)
        const unsigned short rc = s_rc[p0 + nlane];
        const int r = rc & 255, c = rc >> 8;
        #pragma unroll
        for (int s = 0; s < 2; ++s) {
            const f16x8 xr8 = *(const f16x8*)&xh[4 * s + g][r][0];
            const f16x8 xc8 = *(const f16x8*)&xh[4 * s + g][c][0];
            const f16x8 pr = xr8 * xc8;
            #pragma unroll
            for (int j = 0; j < 8; ++j)
                oacc[s][j] = fmaf(ap, (float)pr[j], oacc[s][j]);   // e = 32s+8g+j
        }
    }
    #pragma unroll
    for (int off = 1; off < 16; off <<= 1)
        #pragma unroll
        for (int s = 0; s < 2; ++s)
            #pragma unroll
            for (int j = 0; j < 8; ++j)
                oacc[s][j] += __shfl_xor(oacc[s][j], off);
    if (nlane == 0) {
        #pragma unroll
        for (int s = 0; s < 2; ++s) {
            f32x4 q0 = { oacc[s][0], oacc[s][1], oacc[s][2], oacc[s][3] };
            f32x4 q1 = { oacc[s][4], oacc[s][5], oacc[s][6], oacc[s][7] };
            *(f32x4*)&s_accv[wv][32 * s + 8 * g]     = q0;
            *(f32x4*)&s_accv[wv][32 * s + 8 * g + 4] = q1;
        }
    }
    __syncthreads();
    if (tid < NE) {
        out[(size_t)b * NE + tid] =
            (s_accv[0][tid] + s_accv[1][tid] + s_accv[2][tid] + s_accv[3][tid]) * inv;
    }
}

extern "C" void kernel_launch(void* const* d_in, const int* in_sizes, int n_in,
                              void* d_out, int out_size, void* d_ws, size_t ws_size,
                              hipStream_t stream) {
    const float* x  = (const float*)d_in[0];
    const float* W1 = (const float*)d_in[1];
    const float* b1 = (const float*)d_in[2];
    const float* w2 = (const float*)d_in[3];
    const float* b2 = (const float*)d_in[4];

    const int B = in_sizes[0] / (NF * NE);     // 2048
    float* out_p  = (float*)d_out;             // (B,1,64) flat
    float* attn_p = (float*)d_out + (size_t)B * NE;  // (B,496,1) flat

    _Float16* wf = nullptr;
    if (ws_size >= 64 * 64 * sizeof(_Float16)) {
        wf = (_Float16*)d_ws;
        prep_w1<<<1, 64, 0, stream>>>(W1, wf);
    }
    afm_fwd<<<B, 256, 0, stream>>>(x, W1, b1, w2, b2, wf, out_p, attn_p);
}

// Round 7
// 23.796 us; speedup vs baseline: 1.4864x; 1.4864x over previous
//
#include <hip/hip_runtime.h>
#include <math.h>

#define NF 32
#define NE 64
#define NA 64
#define NP 496

typedef __attribute__((ext_vector_type(8))) _Float16 f16x8;
typedef __attribute__((ext_vector_type(4))) _Float16 f16x4;
typedef __attribute__((ext_vector_type(4))) float    f32x4;

#define W1T_S 72   // padded stride (f16) of W1t: 144B, 16B-aligned, bank-spread
#define XT_S  40   // padded stride (f16) of xT:   80B, 16B-aligned, bank-spread
#define WT_S  40   // padded stride (f16) of Wt

__global__ __launch_bounds__(256, 2) void afm_fwd(
    const float* __restrict__ x,    // (B,32,64)
    const float* __restrict__ W1,   // (64,64)
    const float* __restrict__ b1,   // (64)
    const float* __restrict__ w2,   // (64,1)
    const float* __restrict__ b2,   // (1)
    float* __restrict__ out,        // (B,64)
    float* __restrict__ attn,       // (B,496)
    int B)
{
    const int tid   = threadIdx.x;
    const int lane  = tid & 63;
    const int wv    = tid >> 6;
    const int nlane = lane & 15;
    const int g     = lane >> 4;

    __shared__ __align__(16) _Float16 W1t[64][W1T_S];      // 9216 B, W1t[a][e]
    __shared__ __align__(16) _Float16 xh[4][8][NF][8];     // 16384 B, per-wave
    __shared__ __align__(16) _Float16 xT[4][NE][XT_S];     // 20480 B, xT[w][e][f]
    __shared__ __align__(16) _Float16 Wt[4][NF][WT_S];     // 10240 B, sym weights
    __shared__ float s_l[4][NP];                           // 7936 B, logits
    __shared__ unsigned short s_rc[512];                   // 1024 B
    // total 65280 B <= 64 KB

    // ---- block-cooperative: W1 -> W1t (f16, transposed), pair table ----
    {
        const int e = tid & 63, a0 = (tid >> 6) << 4;
        const float* wr = W1 + e * NA + a0;
        #pragma unroll
        for (int i = 0; i < 4; ++i) {
            const float4 v = *(const float4*)(wr + 4 * i);
            W1t[a0 + 4*i + 0][e] = (_Float16)v.x;
            W1t[a0 + 4*i + 1][e] = (_Float16)v.y;
            W1t[a0 + 4*i + 2][e] = (_Float16)v.z;
            W1t[a0 + 4*i + 3][e] = (_Float16)v.w;
        }
    }
    for (int p = tid; p < 512; p += 256) {
        const int pp = (p < NP) ? p : NP - 1;
        const float sq = sqrtf((float)(3969 - 8 * pp));
        int r = (int)((63.0f - sq) * 0.5f);
        int st = (r * (63 - r)) >> 1;
        if (pp < st) { --r; st = (r * (63 - r)) >> 1; }
        else { const int st2 = ((r + 1) * (62 - r)) >> 1; if (pp >= st2) { ++r; st = st2; } }
        const int c = pp - st + r + 1;
        s_rc[p] = (unsigned short)(r | (c << 8));
    }
    __syncthreads();   // the only block barrier

    const int b = blockIdx.x * 4 + wv;
    if (b >= B) return;

    // ---- per-wave: stage x[b] -> xh (e-subtiled) and xT (transposed) ----
    const float* __restrict__ xb = x + (size_t)b * (NF * NE);
    {
        const int r = lane >> 1, eh = (lane & 1) << 5;     // 32 floats/lane
        #pragma unroll
        for (int i = 0; i < 8; ++i) {
            const int e0 = eh + 4 * i;
            const float4 v = *(const float4*)(xb + r * NE + e0);
            f16x4 hv = { (_Float16)v.x, (_Float16)v.y, (_Float16)v.z, (_Float16)v.w };
            *(f16x4*)&xh[wv][e0 >> 3][r][e0 & 7] = hv;     // ds_write_b64
            xT[wv][e0 + 0][r] = hv[0];
            xT[wv][e0 + 1][r] = hv[1];
            xT[wv][e0 + 2][r] = hv[2];
            xT[wv][e0 + 3][r] = hv[3];
        }
    }

    // ---- W1 A-frags from LDS (8 x ds_read_b128) ----
    f16x8 w1f[2][4];
    #pragma unroll
    for (int s = 0; s < 2; ++s)
        #pragma unroll
        for (int mt = 0; mt < 4; ++mt)
            w1f[s][mt] = *(const f16x8*)&W1t[mt * 16 + nlane][s * 32 + g * 8];

    f32x4 b1q[4], w2q[4];
    #pragma unroll
    for (int mt = 0; mt < 4; ++mt) {
        b1q[mt] = *(const f32x4*)(b1 + mt * 16 + g * 4);   // a = 16mt+4g+reg
        w2q[mt] = *(const f32x4*)(w2 + mt * 16 + g * 4);
    }
    const float bias2 = b2[0];

    // ---- phase 1: all 31 pair-tiles on this wave ----
    for (int t = 0; t < 31; ++t) {
        const int p0 = t << 4;
        const unsigned short rc = s_rc[p0 + nlane];
        const int r = rc & 255, c = rc >> 8;

        f16x8 af[2];
        #pragma unroll
        for (int s = 0; s < 2; ++s) {
            const f16x8 xr8 = *(const f16x8*)&xh[wv][4 * s + g][r][0];
            const f16x8 xc8 = *(const f16x8*)&xh[wv][4 * s + g][c][0];
            af[s] = xr8 * xc8;
        }
        f32x4 acc[4];
        #pragma unroll
        for (int mt = 0; mt < 4; ++mt) acc[mt] = b1q[mt];
        #pragma unroll
        for (int s = 0; s < 2; ++s)
            #pragma unroll
            for (int mt = 0; mt < 4; ++mt)
                acc[mt] = __builtin_amdgcn_mfma_f32_16x16x32_f16(w1f[s][mt], af[s], acc[mt], 0, 0, 0);

        float logit = 0.0f;
        #pragma unroll
        for (int mt = 0; mt < 4; ++mt) {
            logit = fmaf(fmaxf(acc[mt][0], 0.0f), w2q[mt][0], logit);
            logit = fmaf(fmaxf(acc[mt][1], 0.0f), w2q[mt][1], logit);
            logit = fmaf(fmaxf(acc[mt][2], 0.0f), w2q[mt][2], logit);
            logit = fmaf(fmaxf(acc[mt][3], 0.0f), w2q[mt][3], logit);
        }
        logit += __shfl_xor(logit, 16);
        logit += __shfl_xor(logit, 32);
        if (lane < 16) s_l[wv][p0 + lane] = logit + bias2;
    }

    // ---- softmax: wave-local, max-subtracted ----
    float lv[8];
    float mx = -1e30f;
    #pragma unroll
    for (int k = 0; k < 8; ++k) {
        const int p = (k << 6) + lane;
        lv[k] = (p < NP) ? s_l[wv][p] : -1e30f;
        mx = fmaxf(mx, lv[k]);
    }
    #pragma unroll
    for (int off = 1; off < 64; off <<= 1) mx = fmaxf(mx, __shfl_xor(mx, off));

    float ev[8], se = 0.0f;
    #pragma unroll
    for (int k = 0; k < 8; ++k) {
        const int p = (k << 6) + lane;
        ev[k] = (p < NP) ? __expf(lv[k] - mx) : 0.0f;
        se += ev[k];
    }
    #pragma unroll
    for (int off = 1; off < 64; off <<= 1) se += __shfl_xor(se, off);
    const float inv = 1.0f / se;

    // ---- zero Wt, then scatter attn weights (both triangles, diag stays 0) ----
    #pragma unroll
    for (int i = 0; i < 5; ++i) {
        f16x4 z = { (_Float16)0.f, (_Float16)0.f, (_Float16)0.f, (_Float16)0.f };
        ((f16x4*)&Wt[wv][0][0])[lane + (i << 6)] = z;     // 320 x f16x4 = 32*40
    }
    float* __restrict__ attn_b = attn + (size_t)b * NP;
    #pragma unroll
    for (int k = 0; k < 8; ++k) {
        const int p = (k << 6) + lane;
        if (p < NP) {
            const float w = ev[k] * inv;
            attn_b[p] = w;
            const unsigned short rc = s_rc[p];
            const int r = rc & 255, c = rc >> 8;
            const _Float16 wh = (_Float16)w;
            Wt[wv][r][c] = wh;
            Wt[wv][c][r] = wh;
        }
    }

    // ---- phase 3 as GEMM: Y = Wt(32x32) @ X(32x64); both triangles filled
    // => sum_r x[r,e]*y[r,e] = 2 * sum_{r<c} w_rc x[r,e] x[c,e]  -> scale 0.5
    f16x8 wa[2], xbf[4];
    #pragma unroll
    for (int mt = 0; mt < 2; ++mt)
        wa[mt] = *(const f16x8*)&Wt[wv][mt * 16 + nlane][g * 8];
    #pragma unroll
    for (int nt = 0; nt < 4; ++nt)
        xbf[nt] = *(const f16x8*)&xT[wv][nt * 16 + nlane][g * 8];

    f32x4 y[2][4];
    #pragma unroll
    for (int mt = 0; mt < 2; ++mt)
        #pragma unroll
        for (int nt = 0; nt < 4; ++nt) {
            y[mt][nt] = (f32x4)0.0f;
            y[mt][nt] = __builtin_amdgcn_mfma_f32_16x16x32_f16(wa[mt], xbf[nt], y[mt][nt], 0, 0, 0);
        }

    float po[4] = {0.f, 0.f, 0.f, 0.f};
    #pragma unroll
    for (int nt = 0; nt < 4; ++nt)
        #pragma unroll
        for (int mt = 0; mt < 2; ++mt) {
            const f16x4 xv = *(const f16x4*)&xT[wv][nt * 16 + nlane][mt * 16 + g * 4];
            po[nt] += (float)xv[0] * y[mt][nt][0];
            po[nt] += (float)xv[1] * y[mt][nt][1];
            po[nt] += (float)xv[2] * y[mt][nt][2];
            po[nt] += (float)xv[3] * y[mt][nt][3];
        }
    #pragma unroll
    for (int nt = 0; nt < 4; ++nt) {
        po[nt] += __shfl_xor(po[nt], 16);
        po[nt] += __shfl_xor(po[nt], 32);
    }
    if (lane < 16) {
        float* __restrict__ ob = out + (size_t)b * NE;
        #pragma unroll
        for (int nt = 0; nt < 4; ++nt) ob[nt * 16 + lane] = 0.5f * po[nt];
    }
}

extern "C" void kernel_launch(void* const* d_in, const int* in_sizes, int n_in,
                              void* d_out, int out_size, void* d_ws, size_t ws_size,
                              hipStream_t stream) {
    const float* x  = (const float*)d_in[0];
    const float* W1 = (const float*)d_in[1];
    const float* b1 = (const float*)d_in[2];
    const float* w2 = (const float*)d_in[3];
    const float* b2 = (const float*)d_in[4];

    const int B = in_sizes[0] / (NF * NE);             // 2048
    float* out_p  = (float*)d_out;                     // (B,1,64) flat
    float* attn_p = (float*)d_out + (size_t)B * NE;    // (B,496,1) flat

    afm_fwd<<<(B + 3) / 4, 256, 0, stream>>>(x, W1, b1, w2, b2, out_p, attn_p, B);
}

// Round 8
// 23.375 us; speedup vs baseline: 1.5132x; 1.0180x over previous
//
#include <hip/hip_runtime.h>
#include <math.h>

#define NF 32
#define NE 64
#define NA 64
#define NP 496

typedef __attribute__((ext_vector_type(8))) _Float16 f16x8;
typedef __attribute__((ext_vector_type(4))) _Float16 f16x4;
typedef __attribute__((ext_vector_type(4))) float    f32x4;

#define W1T_S 72   // padded stride (f16) of W1t: 144B, 16B-aligned
#define XT_S  40   // padded stride (f16) of xT:   80B, 16B-aligned
#define WT_S  40   // padded stride (f16) of Wt

// Block = 256 thr = 2 samples x 2 waves. LDS 37.8KB -> 4 blocks/CU = 4 waves/SIMD.
__global__ __launch_bounds__(256, 4) void afm_fwd(
    const float* __restrict__ x,    // (B,32,64)
    const float* __restrict__ W1,   // (64,64)
    const float* __restrict__ b1,   // (64)
    const float* __restrict__ w2,   // (64,1)
    const float* __restrict__ b2,   // (1)
    float* __restrict__ out,        // (B,64)
    float* __restrict__ attn,       // (B,496)
    int B)
{
    const int tid   = threadIdx.x;
    const int lane  = tid & 63;
    const int wv    = tid >> 6;
    const int smp   = wv >> 1;      // sample slot in block (0/1)
    const int sub   = wv & 1;       // wave within the sample pair
    const int nlane = lane & 15;
    const int g     = lane >> 4;

    __shared__ __align__(16) _Float16 W1t[64][W1T_S];      // 9216 B
    __shared__ __align__(16) _Float16 xh[2][8][NF][8];     // 8192 B
    __shared__ __align__(16) _Float16 xT[2][NE][XT_S];     // 10240 B
    __shared__ __align__(16) _Float16 Wt[2][NF][WT_S];     // 5120 B
    __shared__ float s_l[2][NP];                           // 3968 B
    __shared__ unsigned short s_rc[512];                   // 1024 B
    // total 37760 B -> 4 blocks/CU

    // ---- block-cooperative: W1 -> W1t (f16, transposed), pair table ----
    {
        const int e = tid & 63, a0 = (tid >> 6) << 4;
        const float* wr = W1 + e * NA + a0;
        #pragma unroll
        for (int i = 0; i < 4; ++i) {
            const float4 v = *(const float4*)(wr + 4 * i);
            W1t[a0 + 4*i + 0][e] = (_Float16)v.x;
            W1t[a0 + 4*i + 1][e] = (_Float16)v.y;
            W1t[a0 + 4*i + 2][e] = (_Float16)v.z;
            W1t[a0 + 4*i + 3][e] = (_Float16)v.w;
        }
    }
    for (int p = tid; p < 512; p += 256) {
        const int pp = (p < NP) ? p : NP - 1;
        const float sq = sqrtf((float)(3969 - 8 * pp));
        int r = (int)((63.0f - sq) * 0.5f);
        int st = (r * (63 - r)) >> 1;
        if (pp < st) { --r; st = (r * (63 - r)) >> 1; }
        else { const int st2 = ((r + 1) * (62 - r)) >> 1; if (pp >= st2) { ++r; st = st2; } }
        const int c = pp - st + r + 1;
        s_rc[p] = (unsigned short)(r | (c << 8));
    }

    int b = blockIdx.x * 2 + smp;
    if (b >= B) b = B - 1;          // dup-compute guard (benign, keeps barriers uniform)

    // ---- zero Wt[smp] now; zero->scatter ordering rides bar1+bar2 ----
    {
        unsigned int* wz = (unsigned int*)&Wt[smp][0][0];  // 640 u32 per sample
        #pragma unroll
        for (int i = 0; i < 5; ++i) {
            const int idx = i * 64 + lane;
            if (idx < 320) wz[sub * 320 + idx] = 0u;
        }
    }

    // ---- stage x[b] halves -> xh (e-subtiled) and xT (transposed) ----
    const float* __restrict__ xb = x + (size_t)b * (NF * NE);
    {
        const int r  = sub * 16 + (lane >> 2);             // 16 rows per wave
        const int e0 = (lane & 3) << 4;
        #pragma unroll
        for (int i = 0; i < 4; ++i) {
            const int e = e0 + 4 * i;
            const float4 v = *(const float4*)(xb + r * NE + e);
            f16x4 hv = { (_Float16)v.x, (_Float16)v.y, (_Float16)v.z, (_Float16)v.w };
            *(f16x4*)&xh[smp][e >> 3][r][e & 7] = hv;      // ds_write_b64
            xT[smp][e + 0][r] = hv[0];
            xT[smp][e + 1][r] = hv[1];
            xT[smp][e + 2][r] = hv[2];
            xT[smp][e + 3][r] = hv[3];
        }
    }
    __syncthreads();   // bar1: W1t/rc/x-staging/Wt-zero done

    // ---- W1 A-frags from LDS (8 x ds_read_b128) ----
    f16x8 w1f[2][4];
    #pragma unroll
    for (int s = 0; s < 2; ++s)
        #pragma unroll
        for (int mt = 0; mt < 4; ++mt)
            w1f[s][mt] = *(const f16x8*)&W1t[mt * 16 + nlane][s * 32 + g * 8];

    f32x4 b1q[4], w2q[4];
    #pragma unroll
    for (int mt = 0; mt < 4; ++mt) {
        b1q[mt] = *(const f32x4*)(b1 + mt * 16 + g * 4);   // a = 16mt+4g+reg
        w2q[mt] = *(const f32x4*)(w2 + mt * 16 + g * 4);
    }
    const float bias2 = b2[0];

    // ---- phase 1: this wave's tile range (sub0: 0..15, sub1: 16..30) ----
    const int t_end = sub ? 31 : 16;
    #pragma unroll 2
    for (int t = sub * 16; t < t_end; ++t) {
        const int p0 = t << 4;
        const unsigned short rc = s_rc[p0 + nlane];
        const int r = rc & 255, c = rc >> 8;

        f16x8 af[2];
        #pragma unroll
        for (int s = 0; s < 2; ++s) {
            const f16x8 xr8 = *(const f16x8*)&xh[smp][4 * s + g][r][0];
            const f16x8 xc8 = *(const f16x8*)&xh[smp][4 * s + g][c][0];
            af[s] = xr8 * xc8;
        }
        f32x4 acc[4];
        #pragma unroll
        for (int mt = 0; mt < 4; ++mt) acc[mt] = b1q[mt];
        #pragma unroll
        for (int s = 0; s < 2; ++s)
            #pragma unroll
            for (int mt = 0; mt < 4; ++mt)
                acc[mt] = __builtin_amdgcn_mfma_f32_16x16x32_f16(w1f[s][mt], af[s], acc[mt], 0, 0, 0);

        float logit = 0.0f;
        #pragma unroll
        for (int mt = 0; mt < 4; ++mt) {
            logit = fmaf(fmaxf(acc[mt][0], 0.0f), w2q[mt][0], logit);
            logit = fmaf(fmaxf(acc[mt][1], 0.0f), w2q[mt][1], logit);
            logit = fmaf(fmaxf(acc[mt][2], 0.0f), w2q[mt][2], logit);
            logit = fmaf(fmaxf(acc[mt][3], 0.0f), w2q[mt][3], logit);
        }
        logit += __shfl_xor(logit, 16);
        logit += __shfl_xor(logit, 32);
        if (lane < 16) s_l[smp][p0 + lane] = logit + bias2;
    }
    __syncthreads();   // bar2: all 496 logits of both samples in LDS

    // ---- softmax: full 496, duplicated per wave (deterministic) ----
    float lv[8], mx = -1e30f;
    #pragma unroll
    for (int k = 0; k < 8; ++k) {
        const int p = (k << 6) + lane;
        lv[k] = (p < NP) ? s_l[smp][p] : -1e30f;
        mx = fmaxf(mx, lv[k]);
    }
    #pragma unroll
    for (int off = 1; off < 64; off <<= 1) mx = fmaxf(mx, __shfl_xor(mx, off));

    float ev[8], se = 0.0f;
    #pragma unroll
    for (int k = 0; k < 8; ++k) {
        const int p = (k << 6) + lane;
        ev[k] = (p < NP) ? __expf(lv[k] - mx) : 0.0f;
        se += ev[k];
    }
    #pragma unroll
    for (int off = 1; off < 64; off <<= 1) se += __shfl_xor(se, off);
    const float inv = 1.0f / se;

    // ---- scatter this wave's half of the weights; write attn ----
    float* __restrict__ attn_b = attn + (size_t)b * NP;
    #pragma unroll
    for (int k = 0; k < 4; ++k) {
        const int kk = (sub << 2) + k;
        const int p = (kk << 6) + lane;
        if (p < NP) {
            const float w = ev[kk] * inv;
            attn_b[p] = w;
            const unsigned short rc = s_rc[p];
            const int r = rc & 255, c = rc >> 8;
            const _Float16 wh = (_Float16)w;
            Wt[smp][r][c] = wh;
            Wt[smp][c][r] = wh;
        }
    }
    __syncthreads();   // bar3: Wt complete

    // ---- phase 3 as GEMM: Y = Wt @ X; out = 0.5 * sum_r x*y. nt split by sub ----
    f16x8 wa[2], xbf[2];
    #pragma unroll
    for (int mt = 0; mt < 2; ++mt)
        wa[mt] = *(const f16x8*)&Wt[smp][mt * 16 + nlane][g * 8];
    #pragma unroll
    for (int j = 0; j < 2; ++j) {
        const int nt = 2 * sub + j;
        xbf[j] = *(const f16x8*)&xT[smp][nt * 16 + nlane][g * 8];
    }

    f32x4 y[2][2];
    #pragma unroll
    for (int mt = 0; mt < 2; ++mt)
        #pragma unroll
        for (int j = 0; j < 2; ++j) {
            y[mt][j] = (f32x4)0.0f;
            y[mt][j] = __builtin_amdgcn_mfma_f32_16x16x32_f16(wa[mt], xbf[j], y[mt][j], 0, 0, 0);
        }

    float po[2] = {0.f, 0.f};
    #pragma unroll
    for (int j = 0; j < 2; ++j) {
        const int nt = 2 * sub + j;
        #pragma unroll
        for (int mt = 0; mt < 2; ++mt) {
            const f16x4 xv = *(const f16x4*)&xT[smp][nt * 16 + nlane][mt * 16 + g * 4];
            po[j] += (float)xv[0] * y[mt][j][0];
            po[j] += (float)xv[1] * y[mt][j][1];
            po[j] += (float)xv[2] * y[mt][j][2];
            po[j] += (float)xv[3] * y[mt][j][3];
        }
        po[j] += __shfl_xor(po[j], 16);
        po[j] += __shfl_xor(po[j], 32);
    }
    if (lane < 16) {
        float* __restrict__ ob = out + (size_t)b * NE;
        #pragma unroll
        for (int j = 0; j < 2; ++j)
            ob[(2 * sub + j) * 16 + lane] = 0.5f * po[j];
    }
}

extern "C" void kernel_launch(void* const* d_in, const int* in_sizes, int n_in,
                              void* d_out, int out_size, void* d_ws, size_t ws_size,
                              hipStream_t stream) {
    const float* x  = (const float*)d_in[0];
    const float* W1 = (const float*)d_in[1];
    const float* b1 = (const float*)d_in[2];
    const float* w2 = (const float*)d_in[3];
    const float* b2 = (const float*)d_in[4];

    const int B = in_sizes[0] / (NF * NE);             // 2048
    float* out_p  = (float*)d_out;                     // (B,1,64) flat
    float* attn_p = (float*)d_out + (size_t)B * NE;    // (B,496,1) flat

    afm_fwd<<<(B + 1) / 2, 256, 0, stream>>>(x, W1, b1, w2, b2, out_p, attn_p, B);
}

// Round 9
// 22.434 us; speedup vs baseline: 1.5767x; 1.0419x over previous
//
#include <hip/hip_runtime.h>
#include <math.h>

#define NF 32
#define NE 64
#define NA 64
#define NP 496

typedef __attribute__((ext_vector_type(8))) _Float16 f16x8;
typedef __attribute__((ext_vector_type(4))) _Float16 f16x4;
typedef __attribute__((ext_vector_type(4))) float    f32x4;

#define W1T_S 72   // padded stride (f16) of W1t
#define XT_S  40   // padded stride (f16) of xT
#define WT_S  40   // padded stride (f16) of Wt

// Block = 256 thr = 2 samples x 2 waves. LDS 37.8KB -> 4 blocks/CU = 4 waves/SIMD.
__global__ __launch_bounds__(256, 4) void afm_fwd(
    const float* __restrict__ x,    // (B,32,64)
    const float* __restrict__ W1,   // (64,64)
    const float* __restrict__ b1,   // (64)
    const float* __restrict__ w2,   // (64,1)
    const float* __restrict__ b2,   // (1)
    float* __restrict__ out,        // (B,64)
    float* __restrict__ attn,       // (B,496)
    int B)
{
    const int tid   = threadIdx.x;
    const int lane  = tid & 63;
    const int wv    = tid >> 6;
    const int smp   = wv >> 1;      // sample slot in block (0/1)
    const int sub   = wv & 1;       // wave within the sample pair
    const int nlane = lane & 15;
    const int g     = lane >> 4;

    __shared__ __align__(16) _Float16 W1t[64][W1T_S];      // 9216 B
    __shared__ __align__(16) _Float16 xh[2][8][NF][8];     // 8192 B
    __shared__ __align__(16) _Float16 xT[2][NE][XT_S];     // 10240 B
    __shared__ __align__(16) _Float16 Wt[2][NF][WT_S];     // 5120 B
    __shared__ float s_l[2][NP];                           // 3968 B
    __shared__ unsigned short s_rc[512];                   // 1024 B
    // total 37760 B -> 4 blocks/CU

    // ---- block-cooperative: W1 -> W1t (f16, transposed), pair table ----
    {
        const int e = tid & 63, a0 = (tid >> 6) << 4;
        const float* wr = W1 + e * NA + a0;
        #pragma unroll
        for (int i = 0; i < 4; ++i) {
            const float4 v = *(const float4*)(wr + 4 * i);
            W1t[a0 + 4*i + 0][e] = (_Float16)v.x;
            W1t[a0 + 4*i + 1][e] = (_Float16)v.y;
            W1t[a0 + 4*i + 2][e] = (_Float16)v.z;
            W1t[a0 + 4*i + 3][e] = (_Float16)v.w;
        }
    }
    for (int p = tid; p < 512; p += 256) {
        const int pp = (p < NP) ? p : NP - 1;
        const float sq = sqrtf((float)(3969 - 8 * pp));
        int r = (int)((63.0f - sq) * 0.5f);
        int st = (r * (63 - r)) >> 1;
        if (pp < st) { --r; st = (r * (63 - r)) >> 1; }
        else { const int st2 = ((r + 1) * (62 - r)) >> 1; if (pp >= st2) { ++r; st = st2; } }
        const int c = pp - st + r + 1;
        s_rc[p] = (unsigned short)(r | (c << 8));
    }

    int b = blockIdx.x * 2 + smp;
    if (b >= B) b = B - 1;          // benign dup-compute guard

    // ---- zero Wt[smp] (ordering rides bar1+bar2) ----
    {
        unsigned int* wz = (unsigned int*)&Wt[smp][0][0];  // 640 u32 per sample
        #pragma unroll
        for (int i = 0; i < 5; ++i) {
            const int idx = i * 64 + lane;
            if (idx < 320) wz[sub * 320 + idx] = 0u;
        }
    }

    // ---- stage x[b] halves -> xh (e-subtiled) and xT (transposed) ----
    const float* __restrict__ xb = x + (size_t)b * (NF * NE);
    {
        const int r  = sub * 16 + (lane >> 2);             // 16 rows per wave
        const int e0 = (lane & 3) << 4;
        #pragma unroll
        for (int i = 0; i < 4; ++i) {
            const int e = e0 + 4 * i;
            const float4 v = *(const float4*)(xb + r * NE + e);
            f16x4 hv = { (_Float16)v.x, (_Float16)v.y, (_Float16)v.z, (_Float16)v.w };
            *(f16x4*)&xh[smp][e >> 3][r][e & 7] = hv;
            xT[smp][e + 0][r] = hv[0];
            xT[smp][e + 1][r] = hv[1];
            xT[smp][e + 2][r] = hv[2];
            xT[smp][e + 3][r] = hv[3];
        }
    }

    // ---- per-lane (r,c) for striped pairs p = 31*nlane + 16*sub + t ----
    int pr, pc;
    {
        const int p0 = 31 * nlane + 16 * sub;
        const float sq = sqrtf((float)(3969 - 8 * p0));
        int r = (int)((63.0f - sq) * 0.5f);
        int st = (r * (63 - r)) >> 1;
        if (p0 < st) { --r; st = (r * (63 - r)) >> 1; }
        else { const int st2 = ((r + 1) * (62 - r)) >> 1; if (p0 >= st2) { ++r; st = st2; } }
        pr = r;
        pc = p0 - st + r + 1;
    }
    __syncthreads();   // bar1: W1t/rc/x-staging/Wt-zero done

    // ---- W1 A-frags from LDS (8 x ds_read_b128) ----
    f16x8 w1f[2][4];
    #pragma unroll
    for (int s = 0; s < 2; ++s)
        #pragma unroll
        for (int mt = 0; mt < 4; ++mt)
            w1f[s][mt] = *(const f16x8*)&W1t[mt * 16 + nlane][s * 32 + g * 8];

    f32x4 b1q[4], w2q[4];
    #pragma unroll
    for (int mt = 0; mt < 4; ++mt) {
        b1q[mt] = *(const f32x4*)(b1 + mt * 16 + g * 4);   // a = 16mt+4g+reg
        w2q[mt] = *(const f32x4*)(w2 + mt * 16 + g * 4);
    }
    const float bias2 = b2[0];

    // ---- phase 1: 16 (sub0) / 15 (sub1) tiles; rc in registers, no DS gate ----
    #pragma unroll
    for (int t = 0; t < 16; ++t) {
        if (16 * sub + t < 31) {
            f16x8 af[2];
            #pragma unroll
            for (int s = 0; s < 2; ++s) {
                const f16x8 xr8 = *(const f16x8*)&xh[smp][4 * s + g][pr][0];
                const f16x8 xc8 = *(const f16x8*)&xh[smp][4 * s + g][pc][0];
                af[s] = xr8 * xc8;
            }
            f32x4 acc[4];
            #pragma unroll
            for (int mt = 0; mt < 4; ++mt) acc[mt] = b1q[mt];
            __builtin_amdgcn_s_setprio(1);
            #pragma unroll
            for (int s = 0; s < 2; ++s)
                #pragma unroll
                for (int mt = 0; mt < 4; ++mt)
                    acc[mt] = __builtin_amdgcn_mfma_f32_16x16x32_f16(w1f[s][mt], af[s], acc[mt], 0, 0, 0);
            __builtin_amdgcn_s_setprio(0);

            float pl0 = 0.f, pl1 = 0.f, pl2 = 0.f, pl3 = 0.f;
            #pragma unroll
            for (int mt = 0; mt < 4; ++mt) {
                pl0 = fmaf(fmaxf(acc[mt][0], 0.0f), w2q[mt][0], pl0);
                pl1 = fmaf(fmaxf(acc[mt][1], 0.0f), w2q[mt][1], pl1);
                pl2 = fmaf(fmaxf(acc[mt][2], 0.0f), w2q[mt][2], pl2);
                pl3 = fmaf(fmaxf(acc[mt][3], 0.0f), w2q[mt][3], pl3);
            }
            float logit = (pl0 + pl1) + (pl2 + pl3);
            logit += __shfl_xor(logit, 16);
            logit += __shfl_xor(logit, 32);
            if (lane < 16) s_l[smp][31 * lane + 16 * sub + t] = logit + bias2;

            // advance (r,c) -> next pair (branchless)
            ++pc;
            const int wrap = (pc >= 32) ? 1 : 0;
            pr += wrap;
            pc = wrap ? (pr + 1) : pc;
        }
    }
    __syncthreads();   // bar2: all 496 logits of both samples in LDS

    // ---- softmax: full 496, duplicated per wave (deterministic) ----
    float lv[8], mx = -1e30f;
    #pragma unroll
    for (int k = 0; k < 8; ++k) {
        const int p = (k << 6) + lane;
        lv[k] = (p < NP) ? s_l[smp][p] : -1e30f;
        mx = fmaxf(mx, lv[k]);
    }
    #pragma unroll
    for (int off = 1; off < 64; off <<= 1) mx = fmaxf(mx, __shfl_xor(mx, off));

    float ev[8], se = 0.0f;
    #pragma unroll
    for (int k = 0; k < 8; ++k) {
        const int p = (k << 6) + lane;
        ev[k] = (p < NP) ? __expf(lv[k] - mx) : 0.0f;
        se += ev[k];
    }
    #pragma unroll
    for (int off = 1; off < 64; off <<= 1) se += __shfl_xor(se, off);
    const float inv = 1.0f / se;

    // ---- scatter this wave's half of the weights; write attn ----
    float* __restrict__ attn_b = attn + (size_t)b * NP;
    #pragma unroll
    for (int k = 0; k < 4; ++k) {
        const int kk = (sub << 2) + k;
        const int p = (kk << 6) + lane;
        if (p < NP) {
            const float w = ev[kk] * inv;
            attn_b[p] = w;
            const unsigned short rc = s_rc[p];
            const int r = rc & 255, c = rc >> 8;
            const _Float16 wh = (_Float16)w;
            Wt[smp][r][c] = wh;
            Wt[smp][c][r] = wh;
        }
    }
    __syncthreads();   // bar3: Wt complete

    // ---- phase 3 as GEMM: Y = Wt @ X; out = 0.5 * sum_r x*y. nt split by sub ----
    f16x8 wa[2], xbf[2];
    #pragma unroll
    for (int mt = 0; mt < 2; ++mt)
        wa[mt] = *(const f16x8*)&Wt[smp][mt * 16 + nlane][g * 8];
    #pragma unroll
    for (int j = 0; j < 2; ++j) {
        const int nt = 2 * sub + j;
        xbf[j] = *(const f16x8*)&xT[smp][nt * 16 + nlane][g * 8];
    }

    f32x4 y[2][2];
    #pragma unroll
    for (int mt = 0; mt < 2; ++mt)
        #pragma unroll
        for (int j = 0; j < 2; ++j) {
            y[mt][j] = (f32x4)0.0f;
            y[mt][j] = __builtin_amdgcn_mfma_f32_16x16x32_f16(wa[mt], xbf[j], y[mt][j], 0, 0, 0);
        }

    float po[2] = {0.f, 0.f};
    #pragma unroll
    for (int j = 0; j < 2; ++j) {
        const int nt = 2 * sub + j;
        #pragma unroll
        for (int mt = 0; mt < 2; ++mt) {
            const f16x4 xv = *(const f16x4*)&xT[smp][nt * 16 + nlane][mt * 16 + g * 4];
            po[j] += (float)xv[0] * y[mt][j][0];
            po[j] += (float)xv[1] * y[mt][j][1];
            po[j] += (float)xv[2] * y[mt][j][2];
            po[j] += (float)xv[3] * y[mt][j][3];
        }
        po[j] += __shfl_xor(po[j], 16);
        po[j] += __shfl_xor(po[j], 32);
    }
    if (lane < 16) {
        float* __restrict__ ob = out + (size_t)b * NE;
        #pragma unroll
        for (int j = 0; j < 2; ++j)
            ob[(2 * sub + j) * 16 + lane] = 0.5f * po[j];
    }
}

extern "C" void kernel_launch(void* const* d_in, const int* in_sizes, int n_in,
                              void* d_out, int out_size, void* d_ws, size_t ws_size,
                              hipStream_t stream) {
    const float* x  = (const float*)d_in[0];
    const float* W1 = (const float*)d_in[1];
    const float* b1 = (const float*)d_in[2];
    const float* w2 = (const float*)d_in[3];
    const float* b2 = (const float*)d_in[4];

    const int B = in_sizes[0] / (NF * NE);             // 2048
    float* out_p  = (float*)d_out;                     // (B,1,64) flat
    float* attn_p = (float*)d_out + (size_t)B * NE;    // (B,496,1) flat

    afm_fwd<<<(B + 1) / 2, 256, 0, stream>>>(x, W1, b1, w2, b2, out_p, attn_p, B);
}